// Round 3
// baseline (4487.113 us; speedup 1.0000x reference)
//
#include <hip/hip_runtime.h>
#include <math.h>

// Problem constants: B=8, CIN=3, COUT=16, H=W=384
#define BQ   8
#define CIN  3
#define COUT 16
#define HW   (384 * 384)            // 147456
#define NPIX (BQ * HW)              // 1,179,648 pixels
#define NELT ((double)NPIX * COUT)  // 18,874,368 elements of v
#define MAX_ITERS 16

#define TPB       256
#define NBLK      768               // 3 blocks/CU * 256 CU, guaranteed by launch_bounds(256,3)
#define NTHREADS  (NBLK * TPB)      // 196,608
#define PPT       6                 // 196,608 * 6 == NPIX exactly

struct Ctl {
    double sum[MAX_ITERS + 1];      // sum|v| after pre (idx 0) and each body iter
    int    bar_count;
    int    bar_sense;
};

__global__ void k_init(Ctl* c) {
    int t = threadIdx.x;
    if (t <= MAX_ITERS) c->sum[t] = 0.0;
    if (t == 0) { c->bar_count = 0; c->bar_sense = 0; }
}

// block = 256 threads = 4 waves; full block sum returned on tid 0
__device__ __forceinline__ float block_reduce_add(float v) {
    #pragma unroll
    for (int off = 32; off > 0; off >>= 1)
        v += __shfl_down(v, off, 64);
    __shared__ float red[TPB / 64];
    int lane = threadIdx.x & 63;
    int wid  = threadIdx.x >> 6;
    if (lane == 0) red[wid] = v;
    __syncthreads();
    float r = 0.f;
    if (threadIdx.x == 0) {
        #pragma unroll
        for (int i = 0; i < TPB / 64; ++i) r += red[i];
    }
    return r;
}

// Sense-reversing grid barrier. All NBLK blocks are co-resident (launch_bounds
// guarantees >=3 blocks/CU schedulable; grid == 3*256). Device-scope atomics
// cross the per-XCD L2s. local sense lives in shared memory.
__device__ __forceinline__ void grid_barrier(Ctl* c, int* sense_sh) {
    __syncthreads();
    if (threadIdx.x == 0) {
        int next = *sense_sh ^ 1;
        int prev = __hip_atomic_fetch_add(&c->bar_count, 1, __ATOMIC_ACQ_REL,
                                          __HIP_MEMORY_SCOPE_AGENT);
        if (prev == NBLK - 1) {
            __hip_atomic_store(&c->bar_count, 0, __ATOMIC_RELAXED,
                               __HIP_MEMORY_SCOPE_AGENT);
            __hip_atomic_store(&c->bar_sense, next, __ATOMIC_RELEASE,
                               __HIP_MEMORY_SCOPE_AGENT);
        } else {
            while (__hip_atomic_load(&c->bar_sense, __ATOMIC_ACQUIRE,
                                     __HIP_MEMORY_SCOPE_AGENT) != next)
                __builtin_amdgcn_s_sleep(8);
        }
        *sense_sh = next;
    }
    __syncthreads();
}

// Persistent fused kernel: whole pipeline, v lives in registers the whole time.
__global__ __launch_bounds__(TPB, 3) void k_persist(
        const float* __restrict__ x,
        const float* __restrict__ wp, const float* __restrict__ bp,
        const float* __restrict__ wl, const float* __restrict__ bl,
        const float* __restrict__ ws, const float* __restrict__ bs,
        float* __restrict__ out, Ctl* __restrict__ ctl) {
    __shared__ float sWs[COUT * COUT], sWl[COUT * COUT], sBs[COUT], sBl[COUT];
    __shared__ int sense_sh;
    const int t = threadIdx.x;
    sWs[t] = ws[t];                    // TPB == 256 == COUT*COUT
    sWl[t] = wl[t];
    if (t < COUT) { sBs[t] = bs[t]; sBl[t] = bl[t]; }
    if (t == 0) sense_sh = 0;
    __syncthreads();

    const int tid = blockIdx.x * TPB + t;
    float v[PPT][COUT];

    // ---- pre conv: v = wp @ x + bp  (3 -> 16 ch), accumulate sum|v|
    float s = 0.f;
    #pragma unroll
    for (int k = 0; k < PPT; ++k) {
        int p  = tid + k * NTHREADS;   // consecutive lanes -> coalesced
        int b  = p / HW;
        int hw = p - b * HW;
        const float* xb = x + (size_t)b * (CIN * HW) + hw;
        float xin[CIN];
        #pragma unroll
        for (int c = 0; c < CIN; ++c) xin[c] = xb[(size_t)c * HW];
        #pragma unroll
        for (int o = 0; o < COUT; ++o) {
            float a = bp[o];
            #pragma unroll
            for (int c = 0; c < CIN; ++c) a = fmaf(wp[o * CIN + c], xin[c], a);
            v[k][o] = a;
            s += fabsf(a);
        }
    }
    {
        float r = block_reduce_add(s);
        if (t == 0) atomicAdd(&ctl->sum[0], (double)r);
    }
    grid_barrier(ctl, &sense_sh);

    // ---- while (mean|v| < 3): v = 10*(wl @ tanh(ws @ v + bs) + bl)
    int it = 0;
    while (it < MAX_ITERS) {
        double sv = __hip_atomic_load(&ctl->sum[it], __ATOMIC_ACQUIRE,
                                      __HIP_MEMORY_SCOPE_AGENT);
        if (sv / NELT >= 3.0) break;   // uniform across all blocks

        s = 0.f;
        #pragma unroll
        for (int k = 0; k < PPT; ++k) {
            float tt[COUT];
            #pragma unroll
            for (int o = 0; o < COUT; ++o) {
                float a = sBs[o];
                #pragma unroll
                for (int c = 0; c < COUT; ++c)
                    a = fmaf(sWs[o * COUT + c], v[k][c], a);
                tt[o] = tanhf(a);
            }
            #pragma unroll
            for (int o = 0; o < COUT; ++o) {
                float a = sBl[o];
                #pragma unroll
                for (int c = 0; c < COUT; ++c)
                    a = fmaf(sWl[o * COUT + c], tt[c], a);
                a *= 10.f;
                v[k][o] = a;
                s += fabsf(a);
            }
        }
        ++it;
        float r = block_reduce_add(s);
        if (t == 0) atomicAdd(&ctl->sum[it], (double)r);
        grid_barrier(ctl, &sense_sh);
    }

    // ---- final conv: out = ws @ v + bs
    #pragma unroll
    for (int k = 0; k < PPT; ++k) {
        int p  = tid + k * NTHREADS;
        int b  = p / HW;
        int hw = p - b * HW;
        float* ob = out + (size_t)b * (COUT * HW) + hw;
        #pragma unroll
        for (int o = 0; o < COUT; ++o) {
            float a = sBs[o];
            #pragma unroll
            for (int c = 0; c < COUT; ++c)
                a = fmaf(sWs[o * COUT + c], v[k][c], a);
            ob[(size_t)o * HW] = a;
        }
    }
}

extern "C" void kernel_launch(void* const* d_in, const int* in_sizes, int n_in,
                              void* d_out, int out_size, void* d_ws, size_t ws_size,
                              hipStream_t stream) {
    // dict order: x, w_pre, b_pre, w_loop, b_loop, w_shared, b_shared
    const float* x  = (const float*)d_in[0];
    const float* wp = (const float*)d_in[1];
    const float* bp = (const float*)d_in[2];
    const float* wl = (const float*)d_in[3];
    const float* bl = (const float*)d_in[4];
    const float* ws = (const float*)d_in[5];
    const float* bs = (const float*)d_in[6];
    float* out = (float*)d_out;
    Ctl*   ctl = (Ctl*)d_ws;

    k_init<<<1, 64, 0, stream>>>(ctl);
    k_persist<<<NBLK, TPB, 0, stream>>>(x, wp, bp, wl, bl, ws, bs, out, ctl);
}

// Round 4
// 1474.607 us; speedup vs baseline: 3.0429x; 3.0429x over previous
//
#include <hip/hip_runtime.h>
#include <math.h>

// Problem constants: B=8, CIN=3, COUT=16, H=W=384
#define BQ   8
#define CIN  3
#define COUT 16
#define HW   (384 * 384)            // 147456
#define NPIX (BQ * HW)              // 1,179,648 pixels
#define NELT ((double)NPIX * COUT)  // 18,874,368 elements of v
#define MAX_ITERS 16

#define TPB       256
#define NBLK      512               // 2 blocks/CU * 256 CU, guaranteed by launch_bounds(256,2)
#define NTHREADS  (NBLK * TPB)      // 131,072
#define PPT       9                 // 131,072 * 9 == NPIX exactly

struct Ctl {
    double sum[MAX_ITERS + 1];      // sum|v| after pre (idx 0) and each body iter
    int    bar_count;
    int    bar_sense;
};

__global__ void k_init(Ctl* c) {
    int t = threadIdx.x;
    if (t <= MAX_ITERS) c->sum[t] = 0.0;
    if (t == 0) { c->bar_count = 0; c->bar_sense = 0; }
}

// tanh(x) = 1 - 2/(exp(2x)+1); v_exp_f32 + v_rcp_f32, ~5 VALU instrs, ~1e-7 abs err.
// x->+inf: exp=inf, rcp=0 -> 1.  x->-inf: exp=0, rcp(1)=1 -> -1.  x=0 -> 0.
__device__ __forceinline__ float tanh_fast(float x) {
    float e = __expf(2.0f * x);
    return fmaf(-2.0f, __builtin_amdgcn_rcpf(e + 1.0f), 1.0f);
}

// block = 256 threads = 4 waves; full block sum returned on tid 0
__device__ __forceinline__ float block_reduce_add(float v) {
    #pragma unroll
    for (int off = 32; off > 0; off >>= 1)
        v += __shfl_down(v, off, 64);
    __shared__ float red[TPB / 64];
    int lane = threadIdx.x & 63;
    int wid  = threadIdx.x >> 6;
    if (lane == 0) red[wid] = v;
    __syncthreads();
    float r = 0.f;
    if (threadIdx.x == 0) {
        #pragma unroll
        for (int i = 0; i < TPB / 64; ++i) r += red[i];
    }
    return r;
}

// Sense-reversing grid barrier; all NBLK blocks co-resident by construction.
__device__ __forceinline__ void grid_barrier(Ctl* c, int* sense_sh) {
    __syncthreads();
    if (threadIdx.x == 0) {
        int next = *sense_sh ^ 1;
        int prev = __hip_atomic_fetch_add(&c->bar_count, 1, __ATOMIC_ACQ_REL,
                                          __HIP_MEMORY_SCOPE_AGENT);
        if (prev == NBLK - 1) {
            __hip_atomic_store(&c->bar_count, 0, __ATOMIC_RELAXED,
                               __HIP_MEMORY_SCOPE_AGENT);
            __hip_atomic_store(&c->bar_sense, next, __ATOMIC_RELEASE,
                               __HIP_MEMORY_SCOPE_AGENT);
        } else {
            while (__hip_atomic_load(&c->bar_sense, __ATOMIC_ACQUIRE,
                                     __HIP_MEMORY_SCOPE_AGENT) != next)
                __builtin_amdgcn_s_sleep(8);
        }
        *sense_sh = next;
    }
    __syncthreads();
}

// Persistent fused kernel: whole pipeline, v[9][16] lives in VGPRs.
// launch_bounds(256,2): 2 blocks/CU -> VGPR budget 256; state ~200, no spill.
__global__ __launch_bounds__(TPB, 2) void k_persist(
        const float* __restrict__ x,
        const float* __restrict__ wp, const float* __restrict__ bp,
        const float* __restrict__ wl, const float* __restrict__ bl,
        const float* __restrict__ ws, const float* __restrict__ bs,
        float* __restrict__ out, Ctl* __restrict__ ctl) {
    __shared__ float sWs[COUT * COUT], sWl[COUT * COUT], sBs[COUT], sBl[COUT];
    __shared__ int sense_sh;
    const int t = threadIdx.x;
    sWs[t] = ws[t];                    // TPB == 256 == COUT*COUT
    sWl[t] = wl[t];
    if (t < COUT) { sBs[t] = bs[t]; sBl[t] = bl[t]; }
    if (t == 0) sense_sh = 0;
    __syncthreads();

    const int tid = blockIdx.x * TPB + t;
    float v[PPT][COUT];

    // ---- pre conv: v = wp @ x + bp  (3 -> 16 ch), accumulate sum|v|
    float s = 0.f;
    #pragma unroll
    for (int k = 0; k < PPT; ++k) {
        int p  = tid + k * NTHREADS;   // consecutive lanes -> coalesced
        int b  = p / HW;
        int hw = p - b * HW;
        const float* xb = x + (size_t)b * (CIN * HW) + hw;
        float xin[CIN];
        #pragma unroll
        for (int c = 0; c < CIN; ++c) xin[c] = xb[(size_t)c * HW];
        #pragma unroll
        for (int o = 0; o < COUT; ++o) {
            float a = bp[o];
            #pragma unroll
            for (int c = 0; c < CIN; ++c) a = fmaf(wp[o * CIN + c], xin[c], a);
            v[k][o] = a;
            s += fabsf(a);
        }
    }
    {
        float r = block_reduce_add(s);
        if (t == 0) atomicAdd(&ctl->sum[0], (double)r);
    }
    grid_barrier(ctl, &sense_sh);

    // ---- while (mean|v| < 3): v = 10*(wl @ tanh(ws @ v + bs) + bl)
    int it = 0;
    while (it < MAX_ITERS) {
        double sv = __hip_atomic_load(&ctl->sum[it], __ATOMIC_ACQUIRE,
                                      __HIP_MEMORY_SCOPE_AGENT);
        if (sv / NELT >= 3.0) break;   // uniform across all blocks

        s = 0.f;
        #pragma unroll
        for (int k = 0; k < PPT; ++k) {
            float tt[COUT];
            #pragma unroll
            for (int o = 0; o < COUT; ++o) {
                float a = sBs[o];
                #pragma unroll
                for (int c = 0; c < COUT; ++c)
                    a = fmaf(sWs[o * COUT + c], v[k][c], a);
                tt[o] = tanh_fast(a);
            }
            #pragma unroll
            for (int o = 0; o < COUT; ++o) {
                float a = sBl[o];
                #pragma unroll
                for (int c = 0; c < COUT; ++c)
                    a = fmaf(sWl[o * COUT + c], tt[c], a);
                a *= 10.f;
                v[k][o] = a;
                s += fabsf(a);
            }
        }
        ++it;
        float r = block_reduce_add(s);
        if (t == 0) atomicAdd(&ctl->sum[it], (double)r);
        grid_barrier(ctl, &sense_sh);
    }

    // ---- final conv: out = ws @ v + bs
    #pragma unroll
    for (int k = 0; k < PPT; ++k) {
        int p  = tid + k * NTHREADS;
        int b  = p / HW;
        int hw = p - b * HW;
        float* ob = out + (size_t)b * (COUT * HW) + hw;
        #pragma unroll
        for (int o = 0; o < COUT; ++o) {
            float a = sBs[o];
            #pragma unroll
            for (int c = 0; c < COUT; ++c)
                a = fmaf(sWs[o * COUT + c], v[k][c], a);
            ob[(size_t)o * HW] = a;
        }
    }
}

extern "C" void kernel_launch(void* const* d_in, const int* in_sizes, int n_in,
                              void* d_out, int out_size, void* d_ws, size_t ws_size,
                              hipStream_t stream) {
    // dict order: x, w_pre, b_pre, w_loop, b_loop, w_shared, b_shared
    const float* x  = (const float*)d_in[0];
    const float* wp = (const float*)d_in[1];
    const float* bp = (const float*)d_in[2];
    const float* wl = (const float*)d_in[3];
    const float* bl = (const float*)d_in[4];
    const float* ws = (const float*)d_in[5];
    const float* bs = (const float*)d_in[6];
    float* out = (float*)d_out;
    Ctl*   ctl = (Ctl*)d_ws;

    k_init<<<1, 64, 0, stream>>>(ctl);
    k_persist<<<NBLK, TPB, 0, stream>>>(x, wp, bp, wl, bl, ws, bs, out, ctl);
}

// Round 5
// 476.530 us; speedup vs baseline: 9.4162x; 3.0945x over previous
//
#include <hip/hip_runtime.h>
#include <math.h>

// Problem constants: B=8, CIN=3, COUT=16, H=W=384
#define BQ   8
#define CIN  3
#define COUT 16
#define HW   (384 * 384)            // 147456
#define NPIX (BQ * HW)              // 1,179,648 pixels
#define NELT ((double)NPIX * COUT)  // 18,874,368 elements of v
#define MAX_ITERS 16

#define TPB       256
#define NBLK      512               // 2 blocks/CU * 256 CU; co-resident via launch_bounds(256,2)
#define NTHREADS  (NBLK * TPB)      // 131,072
#define PPT       9                 // 131,072 * 9 == NPIX exactly

typedef float vfloat16 __attribute__((ext_vector_type(16)));

struct Ctl {
    double sum[MAX_ITERS + 1];
    int    bar_count;
    int    bar_sense;
};

__global__ void k_init(Ctl* c) {
    int t = threadIdx.x;
    if (t <= MAX_ITERS) c->sum[t] = 0.0;
    if (t == 0) { c->bar_count = 0; c->bar_sense = 0; }
}

// tanh(x) = 1 - 2/(exp(2x)+1): v_exp_f32 + v_rcp_f32, ~5 instrs, ~1e-7 abs err.
__device__ __forceinline__ float tanh_fast(float x) {
    float e = __expf(2.0f * x);
    return fmaf(-2.0f, __builtin_amdgcn_rcpf(e + 1.0f), 1.0f);
}

__device__ __forceinline__ float block_reduce_add(float v) {
    #pragma unroll
    for (int off = 32; off > 0; off >>= 1)
        v += __shfl_down(v, off, 64);
    __shared__ float red[TPB / 64];
    int lane = threadIdx.x & 63;
    int wid  = threadIdx.x >> 6;
    if (lane == 0) red[wid] = v;
    __syncthreads();
    float r = 0.f;
    if (threadIdx.x == 0) {
        #pragma unroll
        for (int i = 0; i < TPB / 64; ++i) r += red[i];
    }
    return r;
}

// Sense-reversing grid barrier; all NBLK blocks co-resident by construction.
__device__ __forceinline__ void grid_barrier(Ctl* c, int* sense_sh) {
    __syncthreads();
    if (threadIdx.x == 0) {
        int next = *sense_sh ^ 1;
        int prev = __hip_atomic_fetch_add(&c->bar_count, 1, __ATOMIC_ACQ_REL,
                                          __HIP_MEMORY_SCOPE_AGENT);
        if (prev == NBLK - 1) {
            __hip_atomic_store(&c->bar_count, 0, __ATOMIC_RELAXED,
                               __HIP_MEMORY_SCOPE_AGENT);
            __hip_atomic_store(&c->bar_sense, next, __ATOMIC_RELEASE,
                               __HIP_MEMORY_SCOPE_AGENT);
        } else {
            while (__hip_atomic_load(&c->bar_sense, __ATOMIC_ACQUIRE,
                                     __HIP_MEMORY_SCOPE_AGENT) != next)
                __builtin_amdgcn_s_sleep(8);
        }
        *sense_sh = next;
    }
    __syncthreads();
}

// ---- per-pixel macros over a NAMED ext-vector (no arrays -> guaranteed SROA) ----

// pre conv: vk = wp @ x + bp  (3 -> 16 ch)
#define PRE_PIXEL(vk, kk)                                                \
    { int p = tid + (kk) * NTHREADS; int b = p / HW; int hw = p - b * HW;\
      const float* xb = x + (size_t)b * (CIN * HW) + hw;                 \
      float x0 = xb[0], x1 = xb[HW], x2 = xb[2 * HW];                    \
      _Pragma("unroll")                                                  \
      for (int o = 0; o < COUT; ++o) {                                   \
          float a = bp[o];                                               \
          a = fmaf(wp[o * CIN + 0], x0, a);                              \
          a = fmaf(wp[o * CIN + 1], x1, a);                              \
          a = fmaf(wp[o * CIN + 2], x2, a);                              \
          vk[o] = a; s += fabsf(a);                                      \
      } }

// body: vk = 10*(wl @ tanh(ws @ vk + bs) + bl)
#define STEP_PIXEL(vk)                                                   \
    { float tt[COUT];                                                    \
      _Pragma("unroll")                                                  \
      for (int o = 0; o < COUT; ++o) {                                   \
          float a = bs[o];                                               \
          _Pragma("unroll")                                              \
          for (int c = 0; c < COUT; ++c)                                 \
              a = fmaf(ws[o * COUT + c], vk[c], a);                      \
          tt[o] = tanh_fast(a);                                          \
      }                                                                  \
      _Pragma("unroll")                                                  \
      for (int o = 0; o < COUT; ++o) {                                   \
          float a = bl[o];                                               \
          _Pragma("unroll")                                              \
          for (int c = 0; c < COUT; ++c)                                 \
              a = fmaf(wl[o * COUT + c], tt[c], a);                      \
          a *= 10.f;                                                     \
          vk[o] = a; s += fabsf(a);                                      \
      } }

// final conv: out = ws @ vk + bs
#define FIN_PIXEL(vk, kk)                                                \
    { int p = tid + (kk) * NTHREADS; int b = p / HW; int hw = p - b * HW;\
      float* ob = out + (size_t)b * (COUT * HW) + hw;                    \
      _Pragma("unroll")                                                  \
      for (int o = 0; o < COUT; ++o) {                                   \
          float a = bs[o];                                               \
          _Pragma("unroll")                                              \
          for (int c = 0; c < COUT; ++c)                                 \
              a = fmaf(ws[o * COUT + c], vk[c], a);                      \
          ob[(size_t)o * HW] = a;                                        \
      } }

__global__ __launch_bounds__(TPB, 2) void k_persist(
        const float* __restrict__ x,
        const float* __restrict__ wp, const float* __restrict__ bp,
        const float* __restrict__ wl, const float* __restrict__ bl,
        const float* __restrict__ ws, const float* __restrict__ bs,
        float* __restrict__ out, Ctl* __restrict__ ctl) {
    __shared__ int sense_sh;
    const int t = threadIdx.x;
    if (t == 0) sense_sh = 0;
    __syncthreads();

    const int tid = blockIdx.x * TPB + t;

    // State: 9 named 16-wide vectors = 144 VGPRs. No array indexing anywhere.
    vfloat16 v0, v1, v2, v3, v4, v5, v6, v7, v8;

    // ---- pre conv + sum|v|
    float s = 0.f;
    PRE_PIXEL(v0, 0) PRE_PIXEL(v1, 1) PRE_PIXEL(v2, 2)
    PRE_PIXEL(v3, 3) PRE_PIXEL(v4, 4) PRE_PIXEL(v5, 5)
    PRE_PIXEL(v6, 6) PRE_PIXEL(v7, 7) PRE_PIXEL(v8, 8)
    {
        float r = block_reduce_add(s);
        if (t == 0) atomicAdd(&ctl->sum[0], (double)r);
    }
    grid_barrier(ctl, &sense_sh);

    // ---- while (mean|v| < 3)
    int it = 0;
    while (it < MAX_ITERS) {
        double sv = __hip_atomic_load(&ctl->sum[it], __ATOMIC_ACQUIRE,
                                      __HIP_MEMORY_SCOPE_AGENT);
        if (sv / NELT >= 3.0) break;   // uniform across all blocks

        s = 0.f;
        STEP_PIXEL(v0) STEP_PIXEL(v1) STEP_PIXEL(v2)
        STEP_PIXEL(v3) STEP_PIXEL(v4) STEP_PIXEL(v5)
        STEP_PIXEL(v6) STEP_PIXEL(v7) STEP_PIXEL(v8)
        ++it;
        float r = block_reduce_add(s);
        if (t == 0) atomicAdd(&ctl->sum[it], (double)r);
        grid_barrier(ctl, &sense_sh);
    }

    // ---- final conv
    FIN_PIXEL(v0, 0) FIN_PIXEL(v1, 1) FIN_PIXEL(v2, 2)
    FIN_PIXEL(v3, 3) FIN_PIXEL(v4, 4) FIN_PIXEL(v5, 5)
    FIN_PIXEL(v6, 6) FIN_PIXEL(v7, 7) FIN_PIXEL(v8, 8)
}

extern "C" void kernel_launch(void* const* d_in, const int* in_sizes, int n_in,
                              void* d_out, int out_size, void* d_ws, size_t ws_size,
                              hipStream_t stream) {
    // dict order: x, w_pre, b_pre, w_loop, b_loop, w_shared, b_shared
    const float* x  = (const float*)d_in[0];
    const float* wp = (const float*)d_in[1];
    const float* bp = (const float*)d_in[2];
    const float* wl = (const float*)d_in[3];
    const float* bl = (const float*)d_in[4];
    const float* ws = (const float*)d_in[5];
    const float* bs = (const float*)d_in[6];
    float* out = (float*)d_out;
    Ctl*   ctl = (Ctl*)d_ws;

    k_init<<<1, 64, 0, stream>>>(ctl);
    k_persist<<<NBLK, TPB, 0, stream>>>(x, wp, bp, wl, bl, ws, bs, out, ctl);
}

// Round 6
// 443.509 us; speedup vs baseline: 10.1173x; 1.0745x over previous
//
#include <hip/hip_runtime.h>
#include <math.h>

// Problem constants: B=8, CIN=3, COUT=16, H=W=384
#define BQ   8
#define CIN  3
#define COUT 16
#define HW   (384 * 384)            // 147456
#define NPIX (BQ * HW)              // 1,179,648 pixels
#define NELT 18874368.0f            // NPIX * COUT
#define MAX_ITERS 16

#define TPB       256
#define NBLK      512               // 2 blocks/CU * 256 CU; co-resident via launch_bounds(256,2)
#define NTHREADS  (NBLK * TPB)      // 131,072
#define PPT       9                 // 131,072 * 9 == NPIX exactly

#define NLEAF        64
#define BLK_PER_LEAF (NBLK / NLEAF) // 8

typedef float vfloat16 __attribute__((ext_vector_type(16)));

struct __align__(64) PadCnt { int cnt; int pad[15]; };  // one cache line each

struct Ctl {
    PadCnt leaf[NLEAF];                       // barrier leaf counters (8-way fan-in)
    PadCnt root;                              // barrier root counter (64-way fan-in)
    PadCnt sense;                             // barrier sense (read-only spin target)
    float  partials[MAX_ITERS + 1][NBLK];     // per-block |v| partial sums, per iteration
};

__global__ void k_init(Ctl* c) {
    int t = threadIdx.x;
    if (t < NLEAF) c->leaf[t].cnt = 0;
    if (t == 0) { c->root.cnt = 0; c->sense.cnt = 0; }
}

// tanh(x) = 1 - 2/(exp(2x)+1): v_exp_f32 + v_rcp_f32, ~5 instrs, ~1e-7 abs err.
__device__ __forceinline__ float tanh_fast(float x) {
    float e = __expf(2.0f * x);
    return fmaf(-2.0f, __builtin_amdgcn_rcpf(e + 1.0f), 1.0f);
}

// block = 256 threads = 4 waves; full block sum returned on tid 0
__device__ __forceinline__ float block_reduce_add(float v) {
    #pragma unroll
    for (int off = 32; off > 0; off >>= 1)
        v += __shfl_down(v, off, 64);
    __shared__ float red[TPB / 64];
    int lane = threadIdx.x & 63;
    int wid  = threadIdx.x >> 6;
    if (lane == 0) red[wid] = v;
    __syncthreads();
    float r = 0.f;
    if (threadIdx.x == 0) {
        #pragma unroll
        for (int i = 0; i < TPB / 64; ++i) r += red[i];
    }
    return r;
}

// Two-level sense-reversing grid barrier: leaf fan-in 8, root fan-in 64.
// No 512-way same-line RMW. All NBLK blocks co-resident by construction.
__device__ __forceinline__ void grid_barrier(Ctl* c, int* sense_sh) {
    __syncthreads();
    if (threadIdx.x == 0) {
        int next = *sense_sh ^ 1;
        int lf = blockIdx.x & (NLEAF - 1);
        int p = __hip_atomic_fetch_add(&c->leaf[lf].cnt, 1, __ATOMIC_ACQ_REL,
                                       __HIP_MEMORY_SCOPE_AGENT);
        if (p == BLK_PER_LEAF - 1) {
            // last of this leaf: reset leaf (ordered before root release below)
            __hip_atomic_store(&c->leaf[lf].cnt, 0, __ATOMIC_RELAXED,
                               __HIP_MEMORY_SCOPE_AGENT);
            int q = __hip_atomic_fetch_add(&c->root.cnt, 1, __ATOMIC_ACQ_REL,
                                           __HIP_MEMORY_SCOPE_AGENT);
            if (q == NLEAF - 1) {
                __hip_atomic_store(&c->root.cnt, 0, __ATOMIC_RELAXED,
                                   __HIP_MEMORY_SCOPE_AGENT);
                __hip_atomic_store(&c->sense.cnt, next, __ATOMIC_RELEASE,
                                   __HIP_MEMORY_SCOPE_AGENT);
            }
        }
        while (__hip_atomic_load(&c->sense.cnt, __ATOMIC_ACQUIRE,
                                 __HIP_MEMORY_SCOPE_AGENT) != next)
            __builtin_amdgcn_s_sleep(4);
        *sense_sh = next;
    }
    __syncthreads();
}

// Deterministic grid sum: wave 0 sums all NBLK partials in a fixed order
// (identical in every block -> bitwise-identical -> uniform decision),
// broadcasts via LDS. Atomic relaxed agent loads dodge stale non-coherent L2.
__device__ __forceinline__ float grid_sum(const float* part, float* bc) {
    int lane = threadIdx.x & 63, wid = threadIdx.x >> 6;
    if (wid == 0) {
        float s = 0.f;
        #pragma unroll
        for (int i = 0; i < NBLK / 64; ++i)
            s += __hip_atomic_load(&part[i * 64 + lane], __ATOMIC_RELAXED,
                                   __HIP_MEMORY_SCOPE_AGENT);
        #pragma unroll
        for (int off = 32; off > 0; off >>= 1)
            s += __shfl_down(s, off, 64);
        if (lane == 0) *bc = s;
    }
    __syncthreads();
    return *bc;
}

// ---- per-pixel macros over NAMED ext-vectors (no arrays -> guaranteed SROA) ----

#define PRE_PIXEL(vk, kk)                                                \
    { int p = tid + (kk) * NTHREADS; int b = p / HW; int hw = p - b * HW;\
      const float* xb = x + (size_t)b * (CIN * HW) + hw;                 \
      float x0 = xb[0], x1 = xb[HW], x2 = xb[2 * HW];                    \
      _Pragma("unroll")                                                  \
      for (int o = 0; o < COUT; ++o) {                                   \
          float a = bp[o];                                               \
          a = fmaf(wp[o * CIN + 0], x0, a);                              \
          a = fmaf(wp[o * CIN + 1], x1, a);                              \
          a = fmaf(wp[o * CIN + 2], x2, a);                              \
          vk[o] = a; s += fabsf(a);                                      \
      } }

#define STEP_PIXEL(vk)                                                   \
    { float tt[COUT];                                                    \
      _Pragma("unroll")                                                  \
      for (int o = 0; o < COUT; ++o) {                                   \
          float a = bs[o];                                               \
          _Pragma("unroll")                                              \
          for (int c = 0; c < COUT; ++c)                                 \
              a = fmaf(ws[o * COUT + c], vk[c], a);                      \
          tt[o] = tanh_fast(a);                                          \
      }                                                                  \
      _Pragma("unroll")                                                  \
      for (int o = 0; o < COUT; ++o) {                                   \
          float a = bl[o];                                               \
          _Pragma("unroll")                                              \
          for (int c = 0; c < COUT; ++c)                                 \
              a = fmaf(wl[o * COUT + c], tt[c], a);                      \
          a *= 10.f;                                                     \
          vk[o] = a; s += fabsf(a);                                      \
      } }

#define FIN_PIXEL(vk, kk)                                                \
    { int p = tid + (kk) * NTHREADS; int b = p / HW; int hw = p - b * HW;\
      float* ob = out + (size_t)b * (COUT * HW) + hw;                    \
      _Pragma("unroll")                                                  \
      for (int o = 0; o < COUT; ++o) {                                   \
          float a = bs[o];                                               \
          _Pragma("unroll")                                              \
          for (int c = 0; c < COUT; ++c)                                 \
              a = fmaf(ws[o * COUT + c], vk[c], a);                      \
          ob[(size_t)o * HW] = a;                                        \
      } }

__global__ __launch_bounds__(TPB, 2) void k_persist(
        const float* __restrict__ x,
        const float* __restrict__ wp, const float* __restrict__ bp,
        const float* __restrict__ wl, const float* __restrict__ bl,
        const float* __restrict__ ws, const float* __restrict__ bs,
        float* __restrict__ out, Ctl* __restrict__ ctl) {
    __shared__ int sense_sh;
    __shared__ float bcast;
    const int t = threadIdx.x;
    if (t == 0) sense_sh = 0;
    __syncthreads();

    const int tid = blockIdx.x * TPB + t;

    // State: 9 named 16-wide vectors = 144 registers. No array indexing anywhere.
    vfloat16 v0, v1, v2, v3, v4, v5, v6, v7, v8;

    // ---- pre conv + |v| partial
    float s = 0.f;
    PRE_PIXEL(v0, 0) PRE_PIXEL(v1, 1) PRE_PIXEL(v2, 2)
    PRE_PIXEL(v3, 3) PRE_PIXEL(v4, 4) PRE_PIXEL(v5, 5)
    PRE_PIXEL(v6, 6) PRE_PIXEL(v7, 7) PRE_PIXEL(v8, 8)
    {
        float r = block_reduce_add(s);
        if (t == 0)
            __hip_atomic_store(&ctl->partials[0][blockIdx.x], r,
                               __ATOMIC_RELAXED, __HIP_MEMORY_SCOPE_AGENT);
    }
    grid_barrier(ctl, &sense_sh);

    // ---- while (mean|v| < 3): v = 10*(wl @ tanh(ws @ v + bs) + bl)
    int it = 0;
    while (it < MAX_ITERS) {
        float total = grid_sum(ctl->partials[it], &bcast);
        if (total >= 3.0f * NELT) break;      // uniform across all blocks

        s = 0.f;
        STEP_PIXEL(v0) STEP_PIXEL(v1) STEP_PIXEL(v2)
        STEP_PIXEL(v3) STEP_PIXEL(v4) STEP_PIXEL(v5)
        STEP_PIXEL(v6) STEP_PIXEL(v7) STEP_PIXEL(v8)
        ++it;
        float r = block_reduce_add(s);
        if (t == 0)
            __hip_atomic_store(&ctl->partials[it][blockIdx.x], r,
                               __ATOMIC_RELAXED, __HIP_MEMORY_SCOPE_AGENT);
        grid_barrier(ctl, &sense_sh);
    }

    // ---- final conv
    FIN_PIXEL(v0, 0) FIN_PIXEL(v1, 1) FIN_PIXEL(v2, 2)
    FIN_PIXEL(v3, 3) FIN_PIXEL(v4, 4) FIN_PIXEL(v5, 5)
    FIN_PIXEL(v6, 6) FIN_PIXEL(v7, 7) FIN_PIXEL(v8, 8)
}

extern "C" void kernel_launch(void* const* d_in, const int* in_sizes, int n_in,
                              void* d_out, int out_size, void* d_ws, size_t ws_size,
                              hipStream_t stream) {
    // dict order: x, w_pre, b_pre, w_loop, b_loop, w_shared, b_shared
    const float* x  = (const float*)d_in[0];
    const float* wp = (const float*)d_in[1];
    const float* bp = (const float*)d_in[2];
    const float* wl = (const float*)d_in[3];
    const float* bl = (const float*)d_in[4];
    const float* ws = (const float*)d_in[5];
    const float* bs = (const float*)d_in[6];
    float* out = (float*)d_out;
    Ctl*   ctl = (Ctl*)d_ws;

    k_init<<<1, 64, 0, stream>>>(ctl);
    k_persist<<<NBLK, TPB, 0, stream>>>(x, wp, bp, wl, bl, ws, bs, out, ctl);
}